// Round 3
// baseline (369.697 us; speedup 1.0000x reference)
//
#include <hip/hip_runtime.h>
#include <stdint.h>

#define B_  16
#define L_  1024
#define D_  768
#define K1_ 1536

typedef unsigned short u16;
typedef __attribute__((ext_vector_type(4))) float f32x4;
typedef __attribute__((ext_vector_type(8))) _Float16 f16x8;

__device__ __forceinline__ u16 f2h(float x){
    return __builtin_bit_cast(u16, (_Float16)x);
}
__device__ __forceinline__ void split_h(float x, u16 &hi, u16 &lo){
    _Float16 hh = (_Float16)x;
    hi = __builtin_bit_cast(u16, hh);
    lo = __builtin_bit_cast(u16, (_Float16)(x - (float)hh));
}

__device__ __forceinline__ void gload_lds16(const void* g, void* l){
    __builtin_amdgcn_global_load_lds((const __attribute__((address_space(1))) void*)g,
                                     (__attribute__((address_space(3))) void*)l, 16, 0, 0);
}

// ---------------- prep: A = [h | h+w2] planes, B = [w1 | q] planes ----------------
// hH = fp16(h) (hi only); (wh,wl) = split(h+w2); (qh,ql) = split(q); w1h = fp16(w1) shared
__global__ __launch_bounds__(256) void prep_a(const float* __restrict__ h, const float* __restrict__ q,
    const float* __restrict__ w1w, const float* __restrict__ w2w,
    u16* __restrict__ hH, u16* __restrict__ wh, u16* __restrict__ wl,
    u16* __restrict__ qh, u16* __restrict__ ql, u16* __restrict__ w1h, int b0, int nb)
{
    int idx = blockIdx.x * 256 + threadIdx.x;       // (bb, t, d4)
    int d4 = idx % 192;
    int t  = (idx / 192) & (L_ - 1);
    int bb = idx / (192 * L_);
    if (bb >= nb) return;
    int bg = b0 + bb;
    int d = d4 * 4;

    float4 qv  = *(const float4*)(q   + ((size_t)bg * L_ + t) * D_ + d);
    float4 hv  = *(const float4*)(h   + ((size_t)bg * L_ + t) * D_ + d);
    float4 w2v = *(const float4*)(w2w + (size_t)t * D_ + d);

    size_t o = ((size_t)bb * L_ + t) * D_ + d;
    ushort4 a, b;

    a.x = f2h(hv.x); a.y = f2h(hv.y); a.z = f2h(hv.z); a.w = f2h(hv.w);
    *(ushort4*)(hH + o) = a;

    split_h(hv.x + w2v.x, a.x, b.x); split_h(hv.y + w2v.y, a.y, b.y);
    split_h(hv.z + w2v.z, a.z, b.z); split_h(hv.w + w2v.w, a.w, b.w);
    *(ushort4*)(wh + o) = a;
    *(ushort4*)(wl + o) = b;

    split_h(qv.x, a.x, b.x); split_h(qv.y, a.y, b.y);
    split_h(qv.z, a.z, b.z); split_h(qv.w, a.w, b.w);
    *(ushort4*)(qh + o) = a;
    *(ushort4*)(ql + o) = b;

    if (bb == 0){
        float4 w1v = *(const float4*)(w1w + (size_t)t * D_ + d);
        a.x = f2h(w1v.x); a.y = f2h(w1v.y); a.z = f2h(w1v.z); a.w = f2h(w1v.w);
        *(ushort4*)(w1h + (size_t)t * D_ + d) = a;
    }
}

// ---------------- transpose: qT[b][d][t] = fp16(q[b][t][d]) ----------------
__global__ __launch_bounds__(256) void prep_t(const float* __restrict__ q, u16* __restrict__ qT, int b0)
{
    __shared__ float tile[32][33];
    int bb = blockIdx.z;
    int bg = b0 + bb;
    int t0 = blockIdx.x * 32;
    int d0 = blockIdx.y * 32;
    int tx = threadIdx.x, ty = threadIdx.y;          // 32 x 8
    const float* qb = q + (size_t)bg * L_ * D_;
    #pragma unroll
    for (int i = 0; i < 4; i++){
        int t = t0 + ty + i * 8;
        tile[ty + i * 8][tx] = qb[(size_t)t * D_ + d0 + tx];
    }
    __syncthreads();
    u16* qTb = qT + (size_t)bb * D_ * L_;
    #pragma unroll
    for (int i = 0; i < 4; i++){
        int d = d0 + ty + i * 8;
        qTb[(size_t)d * L_ + t0 + tx] = f2h(tile[tx][ty + i * 8]);
    }
}

// ---------------- GEMM1: a = [h | h+w2] @ [w1 | q]^T + biases ----------------
// region 1 (k<768): single product hH x w1h; region 2: fp16x2 split, 3 products
__global__ __launch_bounds__(256) void gemm1(
    const u16* __restrict__ hH, const u16* __restrict__ wh, const u16* __restrict__ wl,
    const u16* __restrict__ qh, const u16* __restrict__ ql, const u16* __restrict__ w1h,
    const float* __restrict__ w1b, const float* __restrict__ w2b,
    float* __restrict__ aB)
{
    __shared__ u16 ldsA0[128 * 64];
    __shared__ u16 ldsA1[128 * 64];
    __shared__ u16 ldsB0[128 * 64];
    __shared__ u16 ldsB1[128 * 64];
    int bb = blockIdx.y;
    int sm = blockIdx.x >> 3;
    int tn = blockIdx.x & 7;
    int s0 = sm * 128, t0 = tn * 128;
    int tid = threadIdx.x;
    int lane = tid & 63, wid = tid >> 6;
    int wm = wid >> 1, wn = wid & 1;
    int l15 = lane & 15, l4 = lane >> 4;

    const u16* hHb = hH + (size_t)bb * L_ * D_;
    const u16* whb = wh + (size_t)bb * L_ * D_;
    const u16* wlb = wl + (size_t)bb * L_ * D_;
    const u16* qhb = qh + (size_t)bb * L_ * D_;
    const u16* qlb = ql + (size_t)bb * L_ * D_;

    f32x4 acc[4][4];
    #pragma unroll
    for (int m = 0; m < 4; m++)
        #pragma unroll
        for (int n = 0; n < 4; n++)
            acc[m][n] = (f32x4){0.f, 0.f, 0.f, 0.f};

    for (int kb = 0; kb < K1_; kb += 64){
        if (kb < D_){
            #pragma unroll
            for (int j = 0; j < 4; j++){             // stage hH (A rows) + w1h (B rows)
                int n = j * 256 + tid;
                int row = n >> 3, c = n & 7;
                int cc = c ^ (row & 7);              // pre-swizzled global chunk
                int k = kb + cc * 8;
                gload_lds16(hHb + (size_t)(s0 + row) * D_ + k, &ldsA0[(j * 256 + wid * 64) * 8]);
                gload_lds16(w1h + (size_t)(t0 + row) * D_ + k, &ldsB0[(j * 256 + wid * 64) * 8]);
            }
        } else {
            int kb2 = kb - D_;
            #pragma unroll
            for (int j = 0; j < 4; j++){             // stage (h+w2) hi/lo + q hi/lo
                int n = j * 256 + tid;
                int row = n >> 3, c = n & 7;
                int cc = c ^ (row & 7);
                int k = kb2 + cc * 8;
                size_t ao = (size_t)(s0 + row) * D_ + k;
                size_t bo = (size_t)(t0 + row) * D_ + k;
                gload_lds16(whb + ao, &ldsA0[(j * 256 + wid * 64) * 8]);
                gload_lds16(wlb + ao, &ldsA1[(j * 256 + wid * 64) * 8]);
                gload_lds16(qhb + bo, &ldsB0[(j * 256 + wid * 64) * 8]);
                gload_lds16(qlb + bo, &ldsB1[(j * 256 + wid * 64) * 8]);
            }
        }
        __syncthreads();
        if (kb < D_){
            #pragma unroll
            for (int kk = 0; kk < 2; kk++){
                f16x8 ah[4], bh[4];
                #pragma unroll
                for (int m = 0; m < 4; m++){
                    int row = wm * 64 + m * 16 + l15;
                    int c = kk * 4 + l4;
                    ah[m] = *(const f16x8*)&ldsA0[(row * 8 + (c ^ (row & 7))) * 8];
                }
                #pragma unroll
                for (int n = 0; n < 4; n++){
                    int row = wn * 64 + n * 16 + l15;
                    int c = kk * 4 + l4;
                    bh[n] = *(const f16x8*)&ldsB0[(row * 8 + (c ^ (row & 7))) * 8];
                }
                #pragma unroll
                for (int m = 0; m < 4; m++)
                    #pragma unroll
                    for (int n = 0; n < 4; n++)
                        acc[m][n] = __builtin_amdgcn_mfma_f32_16x16x32_f16(ah[m], bh[n], acc[m][n], 0, 0, 0);
            }
        } else {
            #pragma unroll
            for (int kk = 0; kk < 2; kk++){
                f16x8 ah[4], al[4], bh[4], bl[4];
                #pragma unroll
                for (int m = 0; m < 4; m++){
                    int row = wm * 64 + m * 16 + l15;
                    int c = kk * 4 + l4;
                    int off = (row * 8 + (c ^ (row & 7))) * 8;
                    ah[m] = *(const f16x8*)&ldsA0[off];
                    al[m] = *(const f16x8*)&ldsA1[off];
                }
                #pragma unroll
                for (int n = 0; n < 4; n++){
                    int row = wn * 64 + n * 16 + l15;
                    int c = kk * 4 + l4;
                    int off = (row * 8 + (c ^ (row & 7))) * 8;
                    bh[n] = *(const f16x8*)&ldsB0[off];
                    bl[n] = *(const f16x8*)&ldsB1[off];
                }
                #pragma unroll
                for (int m = 0; m < 4; m++)
                    #pragma unroll
                    for (int n = 0; n < 4; n++){
                        acc[m][n] = __builtin_amdgcn_mfma_f32_16x16x32_f16(ah[m], bh[n], acc[m][n], 0, 0, 0);
                        acc[m][n] = __builtin_amdgcn_mfma_f32_16x16x32_f16(ah[m], bl[n], acc[m][n], 0, 0, 0);
                        acc[m][n] = __builtin_amdgcn_mfma_f32_16x16x32_f16(al[m], bh[n], acc[m][n], 0, 0, 0);
                    }
            }
        }
        __syncthreads();
    }

    float* aRow = aB + (size_t)bb * L_ * L_;
    #pragma unroll
    for (int n = 0; n < 4; n++){
        int tcol = t0 + wn * 64 + n * 16 + l15;
        float w1v = w1b[tcol];
        #pragma unroll
        for (int m = 0; m < 4; m++){
            int sbase = s0 + wm * 64 + m * 16 + l4 * 4;
            #pragma unroll
            for (int r = 0; r < 4; r++){
                int s = sbase + r;
                aRow[(size_t)s * L_ + tcol] = acc[m][n][r] + w1v + w2b[s];
            }
        }
    }
}

// ---------------- row softmax: a-row (f32) -> p (fp16, in-place first half), m = rowmax ----------------
__global__ __launch_bounds__(256) void rowsm(float* __restrict__ aB, float* __restrict__ mws, int b0)
{
    __shared__ float red[4];
    int rowid = blockIdx.x;                          // bb*1024 + s
    int bb = rowid >> 10, s = rowid & 1023;
    float* row = aB + (size_t)rowid * L_;
    int tid = threadIdx.x;
    float4 v = ((const float4*)row)[tid];
    float mx = fmaxf(fmaxf(v.x, v.y), fmaxf(v.z, v.w));
    #pragma unroll
    for (int o = 32; o; o >>= 1) mx = fmaxf(mx, __shfl_xor(mx, o));
    if ((tid & 63) == 0) red[tid >> 6] = mx;
    __syncthreads();
    mx = fmaxf(fmaxf(red[0], red[1]), fmaxf(red[2], red[3]));
    float e0 = __expf(v.x - mx), e1 = __expf(v.y - mx), e2 = __expf(v.z - mx), e3 = __expf(v.w - mx);
    float sum = e0 + e1 + e2 + e3;
    #pragma unroll
    for (int o = 32; o; o >>= 1) sum += __shfl_xor(sum, o);
    __syncthreads();
    if ((tid & 63) == 0) red[tid >> 6] = sum;
    __syncthreads();
    sum = red[0] + red[1] + red[2] + red[3];
    float inv = 1.0f / sum;
    ushort4 pk;
    pk.x = f2h(e0 * inv); pk.y = f2h(e1 * inv); pk.z = f2h(e2 * inv); pk.w = f2h(e3 * inv);
    ((ushort4*)row)[tid] = pk;                       // p overwrites first 2KB of its own row
    if (tid == 0) mws[(size_t)(b0 + bb) * L_ + s] = mx;
}

// ---------------- p2 = softmax over s of m (per batch) ----------------
__global__ __launch_bounds__(1024) void p2k(const float* __restrict__ mws, float* __restrict__ p2, int b0)
{
    __shared__ float red[16];
    int bg = b0 + blockIdx.x;
    int tid = threadIdx.x;
    float v = mws[(size_t)bg * L_ + tid];
    float mx = v;
    #pragma unroll
    for (int o = 32; o; o >>= 1) mx = fmaxf(mx, __shfl_xor(mx, o));
    if ((tid & 63) == 0) red[tid >> 6] = mx;
    __syncthreads();
    float m2 = red[0];
    #pragma unroll
    for (int i = 1; i < 16; i++) m2 = fmaxf(m2, red[i]);
    float e = __expf(v - m2);
    float sum = e;
    #pragma unroll
    for (int o = 32; o; o >>= 1) sum += __shfl_xor(sum, o);
    __syncthreads();
    if ((tid & 63) == 0) red[tid >> 6] = sum;
    __syncthreads();
    float st = 0.f;
    #pragma unroll
    for (int i = 0; i < 16; i++) st += red[i];
    p2[(size_t)bg * L_ + tid] = e / st;
}

// ---------------- GEMM2: c = p @ q (fp16), fused output epilogue ----------------
__global__ __launch_bounds__(256) void gemm2(const float* __restrict__ aB, const u16* __restrict__ qT,
    const float* __restrict__ h, const float* __restrict__ p2, float* __restrict__ out, int b0)
{
    __shared__ u16 ldsA[128 * 64];
    __shared__ u16 ldsB[128 * 64];
    int bb = blockIdx.y;
    int bg = b0 + bb;
    int sm = blockIdx.x / 6;
    int dn = blockIdx.x % 6;
    int s0 = sm * 128, d0 = dn * 128;
    int tid = threadIdx.x;
    int lane = tid & 63, wid = tid >> 6;
    int wm = wid >> 1, wn = wid & 1;
    int l15 = lane & 15, l4 = lane >> 4;

    const char* Ab = (const char*)aB + ((size_t)bb * L_) * (L_ * 4);
    const u16* Bb = qT + (size_t)bb * D_ * L_;

    f32x4 acc[4][4];
    #pragma unroll
    for (int m = 0; m < 4; m++)
        #pragma unroll
        for (int n = 0; n < 4; n++)
            acc[m][n] = (f32x4){0.f, 0.f, 0.f, 0.f};

    for (int kb = 0; kb < L_; kb += 64){
        #pragma unroll
        for (int j = 0; j < 4; j++){                 // stage p tile (rows stride 4096B, fp16 payload)
            int n = j * 256 + tid;
            int row = n >> 3, c = n & 7;
            int cc = c ^ (row & 7);
            const u16* g = (const u16*)(Ab + ((size_t)(s0 + row) << 12)) + kb + cc * 8;
            gload_lds16(g, &ldsA[(j * 256 + wid * 64) * 8]);
        }
        #pragma unroll
        for (int j = 0; j < 4; j++){                 // stage qT tile
            int n = j * 256 + tid;
            int row = n >> 3, c = n & 7;
            int cc = c ^ (row & 7);
            const u16* g = Bb + (size_t)(d0 + row) * L_ + kb + cc * 8;
            gload_lds16(g, &ldsB[(j * 256 + wid * 64) * 8]);
        }
        __syncthreads();
        #pragma unroll
        for (int kk = 0; kk < 2; kk++){
            f16x8 af[4], bf[4];
            #pragma unroll
            for (int m = 0; m < 4; m++){
                int row = wm * 64 + m * 16 + l15;
                int c = kk * 4 + l4;
                af[m] = *(const f16x8*)&ldsA[(row * 8 + (c ^ (row & 7))) * 8];
            }
            #pragma unroll
            for (int n = 0; n < 4; n++){
                int row = wn * 64 + n * 16 + l15;
                int c = kk * 4 + l4;
                bf[n] = *(const f16x8*)&ldsB[(row * 8 + (c ^ (row & 7))) * 8];
            }
            #pragma unroll
            for (int m = 0; m < 4; m++)
                #pragma unroll
                for (int n = 0; n < 4; n++)
                    acc[m][n] = __builtin_amdgcn_mfma_f32_16x16x32_f16(af[m], bf[n], acc[m][n], 0, 0, 0);
        }
        __syncthreads();
    }

    #pragma unroll
    for (int m = 0; m < 4; m++){
        int sbase = s0 + wm * 64 + m * 16 + l4 * 4;
        #pragma unroll
        for (int r = 0; r < 4; r++){
            int s = sbase + r;
            float p2v = p2[(size_t)bg * L_ + s];
            size_t hb = ((size_t)bg * L_ + s) * D_;
            size_t ob = ((size_t)bg * L_ + s) * (4 * D_);
            #pragma unroll
            for (int n = 0; n < 4; n++){
                int d = d0 + wn * 64 + n * 16 + l15;
                float cv = acc[m][n][r];
                float hv = h[hb + d];
                float hc = hv * cv;
                out[ob + d]            = hv;
                out[ob + D_ + d]       = cv;
                out[ob + 2 * D_ + d]   = hc;
                out[ob + 3 * D_ + d]   = p2v * hc;
            }
        }
    }
}

extern "C" void kernel_launch(void* const* d_in, const int* in_sizes, int n_in,
                              void* d_out, int out_size, void* d_ws, size_t ws_size,
                              hipStream_t stream)
{
    const float* h   = (const float*)d_in[0];
    const float* q   = (const float*)d_in[1];
    const float* w1w = (const float*)d_in[2];
    const float* w1b = (const float*)d_in[3];
    const float* w2w = (const float*)d_in[4];
    const float* w2b = (const float*)d_in[5];
    float* out = (float*)d_out;

    const size_t szPlane = (size_t)L_ * D_ * 2;      // one fp16 plane, 1.5 MiB
    const size_t szM     = (size_t)B_ * L_ * 4;
    const size_t perB_aB = (size_t)L_ * L_ * 4;
    // per batch: hH, wh, wl, qh, ql (5 planes) + qT + aB
    const size_t perB = 6 * szPlane + perB_aB;       // 13 MiB
    const size_t fixed = szPlane + 2 * szM;          // w1h + mws + p2

    int NB = 1;
    if (ws_size > fixed){
        size_t nbc = (ws_size - fixed) / perB;
        NB = (nbc >= 16) ? 16 : (nbc < 1 ? 1 : (int)nbc);
    }

    char* p = (char*)d_ws;
    u16*   w1h  = (u16*)p;   p += szPlane;
    float* mws  = (float*)p; p += szM;
    float* p2   = (float*)p; p += szM;
    u16*   hH   = (u16*)p;   p += szPlane * NB;
    u16*   wh   = (u16*)p;   p += szPlane * NB;
    u16*   wl   = (u16*)p;   p += szPlane * NB;
    u16*   qh   = (u16*)p;   p += szPlane * NB;
    u16*   ql   = (u16*)p;   p += szPlane * NB;
    u16*   qT   = (u16*)p;   p += szPlane * NB;
    float* aB   = (float*)p;

    for (int b0 = 0; b0 < B_; b0 += NB){
        int nb = (B_ - b0 < NB) ? (B_ - b0) : NB;
        prep_a<<<dim3(nb * 768), 256, 0, stream>>>(h, q, w1w, w2w, hH, wh, wl, qh, ql, w1h, b0, nb);
        prep_t<<<dim3(32, 24, nb), dim3(32, 8), 0, stream>>>(q, qT, b0);
        gemm1 <<<dim3(64, nb), 256, 0, stream>>>(hH, wh, wl, qh, ql, w1h, w1b, w2b, aB);
        rowsm <<<dim3(nb * 1024), 256, 0, stream>>>(aB, mws, b0);
        p2k   <<<dim3(nb), 1024, 0, stream>>>(mws, p2, b0);
        gemm2 <<<dim3(48, nb), 256, 0, stream>>>(aB, qT, h, p2, out, b0);
    }
}

// Round 4
// 259.438 us; speedup vs baseline: 1.4250x; 1.4250x over previous
//
#include <hip/hip_runtime.h>
#include <stdint.h>

#define B_  16
#define L_  1024
#define D_  768
#define K1_ 1536

typedef unsigned short u16;
typedef __attribute__((ext_vector_type(4))) float f32x4;
typedef __attribute__((ext_vector_type(8))) _Float16 f16x8;

__device__ __forceinline__ u16 f2h(float x){
    return __builtin_bit_cast(u16, (_Float16)x);
}

__device__ __forceinline__ void gload_lds16(const void* g, void* l){
    __builtin_amdgcn_global_load_lds((const __attribute__((address_space(1))) void*)g,
                                     (__attribute__((address_space(3))) void*)l, 16, 0, 0);
}

// ---------------- prep: A = [h | h+w2] fp16 planes, B = [w1 | q] fp16 planes ----------------
__global__ __launch_bounds__(256) void prep_a(const float* __restrict__ h, const float* __restrict__ q,
    const float* __restrict__ w1w, const float* __restrict__ w2w,
    u16* __restrict__ hH, u16* __restrict__ wH,
    u16* __restrict__ qH, u16* __restrict__ w1h, int b0, int nb)
{
    int idx = blockIdx.x * 256 + threadIdx.x;       // (bb, t, d4)
    int d4 = idx % 192;
    int t  = (idx / 192) & (L_ - 1);
    int bb = idx / (192 * L_);
    if (bb >= nb) return;
    int bg = b0 + bb;
    int d = d4 * 4;

    float4 qv  = *(const float4*)(q   + ((size_t)bg * L_ + t) * D_ + d);
    float4 hv  = *(const float4*)(h   + ((size_t)bg * L_ + t) * D_ + d);
    float4 w2v = *(const float4*)(w2w + (size_t)t * D_ + d);

    size_t o = ((size_t)bb * L_ + t) * D_ + d;
    ushort4 a;

    a.x = f2h(hv.x); a.y = f2h(hv.y); a.z = f2h(hv.z); a.w = f2h(hv.w);
    *(ushort4*)(hH + o) = a;

    a.x = f2h(hv.x + w2v.x); a.y = f2h(hv.y + w2v.y);
    a.z = f2h(hv.z + w2v.z); a.w = f2h(hv.w + w2v.w);
    *(ushort4*)(wH + o) = a;

    a.x = f2h(qv.x); a.y = f2h(qv.y); a.z = f2h(qv.z); a.w = f2h(qv.w);
    *(ushort4*)(qH + o) = a;

    if (bb == 0){
        float4 w1v = *(const float4*)(w1w + (size_t)t * D_ + d);
        a.x = f2h(w1v.x); a.y = f2h(w1v.y); a.z = f2h(w1v.z); a.w = f2h(w1v.w);
        *(ushort4*)(w1h + (size_t)t * D_ + d) = a;
    }
}

// ---------------- transpose: qT[b][d][t] = fp16(q[b][t][d]) ----------------
__global__ __launch_bounds__(256) void prep_t(const float* __restrict__ q, u16* __restrict__ qT, int b0)
{
    __shared__ float tile[32][33];
    int bb = blockIdx.z;
    int bg = b0 + bb;
    int t0 = blockIdx.x * 32;
    int d0 = blockIdx.y * 32;
    int tx = threadIdx.x, ty = threadIdx.y;          // 32 x 8
    const float* qb = q + (size_t)bg * L_ * D_;
    #pragma unroll
    for (int i = 0; i < 4; i++){
        int t = t0 + ty + i * 8;
        tile[ty + i * 8][tx] = qb[(size_t)t * D_ + d0 + tx];
    }
    __syncthreads();
    u16* qTb = qT + (size_t)bb * D_ * L_;
    #pragma unroll
    for (int i = 0; i < 4; i++){
        int d = d0 + ty + i * 8;
        qTb[(size_t)d * L_ + t0 + tx] = f2h(tile[tx][ty + i * 8]);
    }
}

// ---------------- GEMM1: a = [h | h+w2] @ [w1 | q]^T + biases, single fp16 product ----------------
__global__ __launch_bounds__(256) void gemm1(
    const u16* __restrict__ hH, const u16* __restrict__ wH,
    const u16* __restrict__ qH, const u16* __restrict__ w1h,
    const float* __restrict__ w1b, const float* __restrict__ w2b,
    float* __restrict__ aB)
{
    __shared__ u16 ldsA[128 * 64];
    __shared__ u16 ldsB[128 * 64];
    int bb = blockIdx.y;
    int sm = blockIdx.x >> 3;
    int tn = blockIdx.x & 7;
    int s0 = sm * 128, t0 = tn * 128;
    int tid = threadIdx.x;
    int lane = tid & 63, wid = tid >> 6;
    int wm = wid >> 1, wn = wid & 1;
    int l15 = lane & 15, l4 = lane >> 4;

    const u16* hHb = hH + (size_t)bb * L_ * D_;
    const u16* wHb = wH + (size_t)bb * L_ * D_;
    const u16* qHb = qH + (size_t)bb * L_ * D_;

    f32x4 acc[4][4];
    #pragma unroll
    for (int m = 0; m < 4; m++)
        #pragma unroll
        for (int n = 0; n < 4; n++)
            acc[m][n] = (f32x4){0.f, 0.f, 0.f, 0.f};

    for (int kb = 0; kb < K1_; kb += 64){
        bool inH = (kb < D_);
        const u16* Asrc = inH ? hHb : wHb;           // A rows (s-indexed)
        const u16* Bsrc = inH ? w1h : qHb;           // B rows (t-indexed)
        int koff = inH ? kb : (kb - D_);
        #pragma unroll
        for (int j = 0; j < 4; j++){                 // stage A + B tiles (128 rows x 64 k each)
            int n = j * 256 + tid;
            int row = n >> 3, c = n & 7;
            int cc = c ^ (row & 7);                  // pre-swizzled global chunk
            int k = koff + cc * 8;
            gload_lds16(Asrc + (size_t)(s0 + row) * D_ + k, &ldsA[(j * 256 + wid * 64) * 8]);
            gload_lds16(Bsrc + (size_t)(t0 + row) * D_ + k, &ldsB[(j * 256 + wid * 64) * 8]);
        }
        __syncthreads();
        #pragma unroll
        for (int kk = 0; kk < 2; kk++){
            f16x8 af[4], bf[4];
            #pragma unroll
            for (int m = 0; m < 4; m++){
                int row = wm * 64 + m * 16 + l15;
                int c = kk * 4 + l4;
                af[m] = *(const f16x8*)&ldsA[(row * 8 + (c ^ (row & 7))) * 8];
            }
            #pragma unroll
            for (int n = 0; n < 4; n++){
                int row = wn * 64 + n * 16 + l15;
                int c = kk * 4 + l4;
                bf[n] = *(const f16x8*)&ldsB[(row * 8 + (c ^ (row & 7))) * 8];
            }
            #pragma unroll
            for (int m = 0; m < 4; m++)
                #pragma unroll
                for (int n = 0; n < 4; n++)
                    acc[m][n] = __builtin_amdgcn_mfma_f32_16x16x32_f16(af[m], bf[n], acc[m][n], 0, 0, 0);
        }
        __syncthreads();
    }

    float* aRow = aB + (size_t)bb * L_ * L_;
    #pragma unroll
    for (int n = 0; n < 4; n++){
        int tcol = t0 + wn * 64 + n * 16 + l15;
        float w1v = w1b[tcol];
        #pragma unroll
        for (int m = 0; m < 4; m++){
            int sbase = s0 + wm * 64 + m * 16 + l4 * 4;
            #pragma unroll
            for (int r = 0; r < 4; r++){
                int s = sbase + r;
                aRow[(size_t)s * L_ + tcol] = acc[m][n][r] + w1v + w2b[s];
            }
        }
    }
}

// ---------------- row softmax: a-row (f32) -> p (fp16, in-place first half), m = rowmax ----------------
__global__ __launch_bounds__(256) void rowsm(float* __restrict__ aB, float* __restrict__ mws, int b0)
{
    __shared__ float red[4];
    int rowid = blockIdx.x;                          // bb*1024 + s
    int bb = rowid >> 10, s = rowid & 1023;
    float* row = aB + (size_t)rowid * L_;
    int tid = threadIdx.x;
    float4 v = ((const float4*)row)[tid];
    float mx = fmaxf(fmaxf(v.x, v.y), fmaxf(v.z, v.w));
    #pragma unroll
    for (int o = 32; o; o >>= 1) mx = fmaxf(mx, __shfl_xor(mx, o));
    if ((tid & 63) == 0) red[tid >> 6] = mx;
    __syncthreads();
    mx = fmaxf(fmaxf(red[0], red[1]), fmaxf(red[2], red[3]));
    float e0 = __expf(v.x - mx), e1 = __expf(v.y - mx), e2 = __expf(v.z - mx), e3 = __expf(v.w - mx);
    float sum = e0 + e1 + e2 + e3;
    #pragma unroll
    for (int o = 32; o; o >>= 1) sum += __shfl_xor(sum, o);
    __syncthreads();
    if ((tid & 63) == 0) red[tid >> 6] = sum;
    __syncthreads();
    sum = red[0] + red[1] + red[2] + red[3];
    float inv = 1.0f / sum;
    ushort4 pk;
    pk.x = f2h(e0 * inv); pk.y = f2h(e1 * inv); pk.z = f2h(e2 * inv); pk.w = f2h(e3 * inv);
    ((ushort4*)row)[tid] = pk;                       // p overwrites first 2KB of its own row
    if (tid == 0) mws[(size_t)(b0 + bb) * L_ + s] = mx;
}

// ---------------- p2 = softmax over s of m (per batch) ----------------
__global__ __launch_bounds__(1024) void p2k(const float* __restrict__ mws, float* __restrict__ p2, int b0)
{
    __shared__ float red[16];
    int bg = b0 + blockIdx.x;
    int tid = threadIdx.x;
    float v = mws[(size_t)bg * L_ + tid];
    float mx = v;
    #pragma unroll
    for (int o = 32; o; o >>= 1) mx = fmaxf(mx, __shfl_xor(mx, o));
    if ((tid & 63) == 0) red[tid >> 6] = mx;
    __syncthreads();
    float m2 = red[0];
    #pragma unroll
    for (int i = 1; i < 16; i++) m2 = fmaxf(m2, red[i]);
    float e = __expf(v - m2);
    float sum = e;
    #pragma unroll
    for (int o = 32; o; o >>= 1) sum += __shfl_xor(sum, o);
    __syncthreads();
    if ((tid & 63) == 0) red[tid >> 6] = sum;
    __syncthreads();
    float st = 0.f;
    #pragma unroll
    for (int i = 0; i < 16; i++) st += red[i];
    p2[(size_t)bg * L_ + tid] = e / st;
}

// ---------------- GEMM2: c = p @ q (fp16), fused output epilogue ----------------
__global__ __launch_bounds__(256) void gemm2(const float* __restrict__ aB, const u16* __restrict__ qT,
    const float* __restrict__ h, const float* __restrict__ p2, float* __restrict__ out, int b0)
{
    __shared__ u16 ldsA[128 * 64];
    __shared__ u16 ldsB[128 * 64];
    int bb = blockIdx.y;
    int bg = b0 + bb;
    int sm = blockIdx.x / 6;
    int dn = blockIdx.x % 6;
    int s0 = sm * 128, d0 = dn * 128;
    int tid = threadIdx.x;
    int lane = tid & 63, wid = tid >> 6;
    int wm = wid >> 1, wn = wid & 1;
    int l15 = lane & 15, l4 = lane >> 4;

    const char* Ab = (const char*)aB + ((size_t)bb * L_) * (L_ * 4);
    const u16* Bb = qT + (size_t)bb * D_ * L_;

    f32x4 acc[4][4];
    #pragma unroll
    for (int m = 0; m < 4; m++)
        #pragma unroll
        for (int n = 0; n < 4; n++)
            acc[m][n] = (f32x4){0.f, 0.f, 0.f, 0.f};

    for (int kb = 0; kb < L_; kb += 64){
        #pragma unroll
        for (int j = 0; j < 4; j++){                 // stage p tile (rows stride 4096B, fp16 payload)
            int n = j * 256 + tid;
            int row = n >> 3, c = n & 7;
            int cc = c ^ (row & 7);
            const u16* g = (const u16*)(Ab + ((size_t)(s0 + row) << 12)) + kb + cc * 8;
            gload_lds16(g, &ldsA[(j * 256 + wid * 64) * 8]);
        }
        #pragma unroll
        for (int j = 0; j < 4; j++){                 // stage qT tile
            int n = j * 256 + tid;
            int row = n >> 3, c = n & 7;
            int cc = c ^ (row & 7);
            const u16* g = Bb + (size_t)(d0 + row) * L_ + kb + cc * 8;
            gload_lds16(g, &ldsB[(j * 256 + wid * 64) * 8]);
        }
        __syncthreads();
        #pragma unroll
        for (int kk = 0; kk < 2; kk++){
            f16x8 af[4], bf[4];
            #pragma unroll
            for (int m = 0; m < 4; m++){
                int row = wm * 64 + m * 16 + l15;
                int c = kk * 4 + l4;
                af[m] = *(const f16x8*)&ldsA[(row * 8 + (c ^ (row & 7))) * 8];
            }
            #pragma unroll
            for (int n = 0; n < 4; n++){
                int row = wn * 64 + n * 16 + l15;
                int c = kk * 4 + l4;
                bf[n] = *(const f16x8*)&ldsB[(row * 8 + (c ^ (row & 7))) * 8];
            }
            #pragma unroll
            for (int m = 0; m < 4; m++)
                #pragma unroll
                for (int n = 0; n < 4; n++)
                    acc[m][n] = __builtin_amdgcn_mfma_f32_16x16x32_f16(af[m], bf[n], acc[m][n], 0, 0, 0);
        }
        __syncthreads();
    }

    #pragma unroll
    for (int m = 0; m < 4; m++){
        int sbase = s0 + wm * 64 + m * 16 + l4 * 4;
        #pragma unroll
        for (int r = 0; r < 4; r++){
            int s = sbase + r;
            float p2v = p2[(size_t)bg * L_ + s];
            size_t hb = ((size_t)bg * L_ + s) * D_;
            size_t ob = ((size_t)bg * L_ + s) * (4 * D_);
            #pragma unroll
            for (int n = 0; n < 4; n++){
                int d = d0 + wn * 64 + n * 16 + l15;
                float cv = acc[m][n][r];
                float hv = h[hb + d];
                float hc = hv * cv;
                out[ob + d]            = hv;
                out[ob + D_ + d]       = cv;
                out[ob + 2 * D_ + d]   = hc;
                out[ob + 3 * D_ + d]   = p2v * hc;
            }
        }
    }
}

extern "C" void kernel_launch(void* const* d_in, const int* in_sizes, int n_in,
                              void* d_out, int out_size, void* d_ws, size_t ws_size,
                              hipStream_t stream)
{
    const float* h   = (const float*)d_in[0];
    const float* q   = (const float*)d_in[1];
    const float* w1w = (const float*)d_in[2];
    const float* w1b = (const float*)d_in[3];
    const float* w2w = (const float*)d_in[4];
    const float* w2b = (const float*)d_in[5];
    float* out = (float*)d_out;

    const size_t szPlane = (size_t)L_ * D_ * 2;      // one fp16 plane, 1.5 MiB
    const size_t szM     = (size_t)B_ * L_ * 4;
    const size_t perB_aB = (size_t)L_ * L_ * 4;
    // per batch: hH, wH, qH, qT (4 planes) + aB
    const size_t perB = 4 * szPlane + perB_aB;       // 10 MiB
    const size_t fixed = szPlane + 2 * szM;          // w1h + mws + p2

    int NB = 1;
    if (ws_size > fixed){
        size_t nbc = (ws_size - fixed) / perB;
        NB = (nbc >= 16) ? 16 : (nbc < 1 ? 1 : (int)nbc);
    }

    char* p = (char*)d_ws;
    u16*   w1h  = (u16*)p;   p += szPlane;
    float* mws  = (float*)p; p += szM;
    float* p2   = (float*)p; p += szM;
    u16*   hH   = (u16*)p;   p += szPlane * NB;
    u16*   wH   = (u16*)p;   p += szPlane * NB;
    u16*   qH   = (u16*)p;   p += szPlane * NB;
    u16*   qT   = (u16*)p;   p += szPlane * NB;
    float* aB   = (float*)p;

    for (int b0 = 0; b0 < B_; b0 += NB){
        int nb = (B_ - b0 < NB) ? (B_ - b0) : NB;
        prep_a<<<dim3(nb * 768), 256, 0, stream>>>(h, q, w1w, w2w, hH, wH, qH, w1h, b0, nb);
        prep_t<<<dim3(32, 24, nb), dim3(32, 8), 0, stream>>>(q, qT, b0);
        gemm1 <<<dim3(64, nb), 256, 0, stream>>>(hH, wH, qH, w1h, w1b, w2b, aB);
        rowsm <<<dim3(nb * 1024), 256, 0, stream>>>(aB, mws, b0);
        p2k   <<<dim3(nb), 1024, 0, stream>>>(mws, p2, b0);
        gemm2 <<<dim3(48, nb), 256, 0, stream>>>(aB, qT, h, p2, out, b0);
    }
}

// Round 5
// 251.227 us; speedup vs baseline: 1.4716x; 1.0327x over previous
//
#include <hip/hip_runtime.h>
#include <stdint.h>

#define B_  16
#define L_  1024
#define D_  768
#define K1_ 1536

typedef unsigned short u16;
typedef __attribute__((ext_vector_type(4))) float f32x4;
typedef __attribute__((ext_vector_type(8))) _Float16 f16x8;

__device__ __forceinline__ u16 f2h(float x){
    return __builtin_bit_cast(u16, (_Float16)x);
}

__device__ __forceinline__ void gload_lds16(const void* g, void* l){
    __builtin_amdgcn_global_load_lds((const __attribute__((address_space(1))) void*)g,
                                     (__attribute__((address_space(3))) void*)l, 16, 0, 0);
}

// ---------------- prep: A = [h | h+w2] fp16 planes, B = [w1 | q] fp16 planes ----------------
__global__ __launch_bounds__(256) void prep_a(const float* __restrict__ h, const float* __restrict__ q,
    const float* __restrict__ w1w, const float* __restrict__ w2w,
    u16* __restrict__ hH, u16* __restrict__ wH,
    u16* __restrict__ qH, u16* __restrict__ w1h, int b0, int nb)
{
    int idx = blockIdx.x * 256 + threadIdx.x;       // (bb, t, d4)
    int d4 = idx % 192;
    int t  = (idx / 192) & (L_ - 1);
    int bb = idx / (192 * L_);
    if (bb >= nb) return;
    int bg = b0 + bb;
    int d = d4 * 4;

    float4 qv  = *(const float4*)(q   + ((size_t)bg * L_ + t) * D_ + d);
    float4 hv  = *(const float4*)(h   + ((size_t)bg * L_ + t) * D_ + d);
    float4 w2v = *(const float4*)(w2w + (size_t)t * D_ + d);

    size_t o = ((size_t)bb * L_ + t) * D_ + d;
    ushort4 a;

    a.x = f2h(hv.x); a.y = f2h(hv.y); a.z = f2h(hv.z); a.w = f2h(hv.w);
    *(ushort4*)(hH + o) = a;

    a.x = f2h(hv.x + w2v.x); a.y = f2h(hv.y + w2v.y);
    a.z = f2h(hv.z + w2v.z); a.w = f2h(hv.w + w2v.w);
    *(ushort4*)(wH + o) = a;

    a.x = f2h(qv.x); a.y = f2h(qv.y); a.z = f2h(qv.z); a.w = f2h(qv.w);
    *(ushort4*)(qH + o) = a;

    if (bb == 0){
        float4 w1v = *(const float4*)(w1w + (size_t)t * D_ + d);
        a.x = f2h(w1v.x); a.y = f2h(w1v.y); a.z = f2h(w1v.z); a.w = f2h(w1v.w);
        *(ushort4*)(w1h + (size_t)t * D_ + d) = a;
    }
}

// ---------------- transpose: qT[b][d][t] = fp16(q[b][t][d]) ----------------
__global__ __launch_bounds__(256) void prep_t(const float* __restrict__ q, u16* __restrict__ qT, int b0)
{
    __shared__ float tile[32][33];
    int bb = blockIdx.z;
    int bg = b0 + bb;
    int t0 = blockIdx.x * 32;
    int d0 = blockIdx.y * 32;
    int tx = threadIdx.x, ty = threadIdx.y;          // 32 x 8
    const float* qb = q + (size_t)bg * L_ * D_;
    #pragma unroll
    for (int i = 0; i < 4; i++){
        int t = t0 + ty + i * 8;
        tile[ty + i * 8][tx] = qb[(size_t)t * D_ + d0 + tx];
    }
    __syncthreads();
    u16* qTb = qT + (size_t)bb * D_ * L_;
    #pragma unroll
    for (int i = 0; i < 4; i++){
        int d = d0 + ty + i * 8;
        qTb[(size_t)d * L_ + t0 + tx] = f2h(tile[tx][ty + i * 8]);
    }
}

// ---------------- GEMM1: a = [h | h+w2] @ [w1 | q]^T + biases, single fp16 product ----------------
__global__ __launch_bounds__(256) void gemm1(
    const u16* __restrict__ hH, const u16* __restrict__ wH,
    const u16* __restrict__ qH, const u16* __restrict__ w1h,
    const float* __restrict__ w1b, const float* __restrict__ w2b,
    float* __restrict__ aB)
{
    __shared__ u16 ldsA[128 * 64];
    __shared__ u16 ldsB[128 * 64];
    int bb = blockIdx.y;
    int sm = blockIdx.x >> 3;
    int tn = blockIdx.x & 7;
    int s0 = sm * 128, t0 = tn * 128;
    int tid = threadIdx.x;
    int lane = tid & 63, wid = tid >> 6;
    int wm = wid >> 1, wn = wid & 1;
    int l15 = lane & 15, l4 = lane >> 4;

    const u16* hHb = hH + (size_t)bb * L_ * D_;
    const u16* wHb = wH + (size_t)bb * L_ * D_;
    const u16* qHb = qH + (size_t)bb * L_ * D_;

    f32x4 acc[4][4];
    #pragma unroll
    for (int m = 0; m < 4; m++)
        #pragma unroll
        for (int n = 0; n < 4; n++)
            acc[m][n] = (f32x4){0.f, 0.f, 0.f, 0.f};

    for (int kb = 0; kb < K1_; kb += 64){
        bool inH = (kb < D_);
        const u16* Asrc = inH ? hHb : wHb;           // A rows (s-indexed)
        const u16* Bsrc = inH ? w1h : qHb;           // B rows (t-indexed)
        int koff = inH ? kb : (kb - D_);
        #pragma unroll
        for (int j = 0; j < 4; j++){                 // stage A + B tiles (128 rows x 64 k each)
            int n = j * 256 + tid;
            int row = n >> 3, c = n & 7;
            int cc = c ^ (row & 7);                  // pre-swizzled global chunk
            int k = koff + cc * 8;
            gload_lds16(Asrc + (size_t)(s0 + row) * D_ + k, &ldsA[(j * 256 + wid * 64) * 8]);
            gload_lds16(Bsrc + (size_t)(t0 + row) * D_ + k, &ldsB[(j * 256 + wid * 64) * 8]);
        }
        __syncthreads();
        #pragma unroll
        for (int kk = 0; kk < 2; kk++){
            f16x8 af[4], bf[4];
            #pragma unroll
            for (int m = 0; m < 4; m++){
                int row = wm * 64 + m * 16 + l15;
                int c = kk * 4 + l4;
                af[m] = *(const f16x8*)&ldsA[(row * 8 + (c ^ (row & 7))) * 8];
            }
            #pragma unroll
            for (int n = 0; n < 4; n++){
                int row = wn * 64 + n * 16 + l15;
                int c = kk * 4 + l4;
                bf[n] = *(const f16x8*)&ldsB[(row * 8 + (c ^ (row & 7))) * 8];
            }
            #pragma unroll
            for (int m = 0; m < 4; m++)
                #pragma unroll
                for (int n = 0; n < 4; n++)
                    acc[m][n] = __builtin_amdgcn_mfma_f32_16x16x32_f16(af[m], bf[n], acc[m][n], 0, 0, 0);
        }
        __syncthreads();
    }

    float* aRow = aB + (size_t)bb * L_ * L_;
    #pragma unroll
    for (int n = 0; n < 4; n++){
        int tcol = t0 + wn * 64 + n * 16 + l15;
        float w1v = w1b[tcol];
        #pragma unroll
        for (int m = 0; m < 4; m++){
            int sbase = s0 + wm * 64 + m * 16 + l4 * 4;
            #pragma unroll
            for (int r = 0; r < 4; r++){
                int s = sbase + r;
                aRow[(size_t)s * L_ + tcol] = acc[m][n][r] + w1v + w2b[s];
            }
        }
    }
}

// ---------------- row softmax: a-row (f32) -> pB (fp16 compact), m = rowmax ----------------
__global__ __launch_bounds__(256) void rowsm(const float* __restrict__ aB, u16* __restrict__ pB,
                                             float* __restrict__ mws, int b0)
{
    __shared__ float red[4];
    int rowid = blockIdx.x;                          // bb*1024 + s
    int bb = rowid >> 10, s = rowid & 1023;
    const float* row = aB + (size_t)rowid * L_;
    int tid = threadIdx.x;
    float4 v = ((const float4*)row)[tid];
    float mx = fmaxf(fmaxf(v.x, v.y), fmaxf(v.z, v.w));
    #pragma unroll
    for (int o = 32; o; o >>= 1) mx = fmaxf(mx, __shfl_xor(mx, o));
    if ((tid & 63) == 0) red[tid >> 6] = mx;
    __syncthreads();
    mx = fmaxf(fmaxf(red[0], red[1]), fmaxf(red[2], red[3]));
    float e0 = __expf(v.x - mx), e1 = __expf(v.y - mx), e2 = __expf(v.z - mx), e3 = __expf(v.w - mx);
    float sum = e0 + e1 + e2 + e3;
    #pragma unroll
    for (int o = 32; o; o >>= 1) sum += __shfl_xor(sum, o);
    __syncthreads();
    if ((tid & 63) == 0) red[tid >> 6] = sum;
    __syncthreads();
    sum = red[0] + red[1] + red[2] + red[3];
    float inv = 1.0f / sum;
    ushort4 pk;
    pk.x = f2h(e0 * inv); pk.y = f2h(e1 * inv); pk.z = f2h(e2 * inv); pk.w = f2h(e3 * inv);
    ((ushort4*)(pB + (size_t)rowid * L_))[tid] = pk;
    if (tid == 0) mws[(size_t)(b0 + bb) * L_ + s] = mx;
}

// ---------------- p2 = softmax over s of m (per batch) ----------------
__global__ __launch_bounds__(1024) void p2k(const float* __restrict__ mws, float* __restrict__ p2, int b0)
{
    __shared__ float red[16];
    int bg = b0 + blockIdx.x;
    int tid = threadIdx.x;
    float v = mws[(size_t)bg * L_ + tid];
    float mx = v;
    #pragma unroll
    for (int o = 32; o; o >>= 1) mx = fmaxf(mx, __shfl_xor(mx, o));
    if ((tid & 63) == 0) red[tid >> 6] = mx;
    __syncthreads();
    float m2 = red[0];
    #pragma unroll
    for (int i = 1; i < 16; i++) m2 = fmaxf(m2, red[i]);
    float e = __expf(v - m2);
    float sum = e;
    #pragma unroll
    for (int o = 32; o; o >>= 1) sum += __shfl_xor(sum, o);
    __syncthreads();
    if ((tid & 63) == 0) red[tid >> 6] = sum;
    __syncthreads();
    float st = 0.f;
    #pragma unroll
    for (int i = 0; i < 16; i++) st += red[i];
    p2[(size_t)bg * L_ + tid] = e / st;
}

// ---------------- GEMM2 core: c = p @ q (fp16 in, f32 dense out) ----------------
__global__ __launch_bounds__(256) void gemm2(const u16* __restrict__ pB, const u16* __restrict__ qT,
    float* __restrict__ cB)
{
    __shared__ u16 ldsA[128 * 64];
    __shared__ u16 ldsB[128 * 64];
    int bb = blockIdx.y;
    int sm = blockIdx.x / 6;
    int dn = blockIdx.x % 6;
    int s0 = sm * 128, d0 = dn * 128;
    int tid = threadIdx.x;
    int lane = tid & 63, wid = tid >> 6;
    int wm = wid >> 1, wn = wid & 1;
    int l15 = lane & 15, l4 = lane >> 4;

    const u16* Ab = pB + (size_t)bb * L_ * L_;
    const u16* Bb = qT + (size_t)bb * D_ * L_;

    f32x4 acc[4][4];
    #pragma unroll
    for (int m = 0; m < 4; m++)
        #pragma unroll
        for (int n = 0; n < 4; n++)
            acc[m][n] = (f32x4){0.f, 0.f, 0.f, 0.f};

    for (int kb = 0; kb < L_; kb += 64){
        #pragma unroll
        for (int j = 0; j < 4; j++){                 // stage p tile (dense fp16, stride 2KB)
            int n = j * 256 + tid;
            int row = n >> 3, c = n & 7;
            int cc = c ^ (row & 7);
            gload_lds16(Ab + (size_t)(s0 + row) * L_ + kb + cc * 8, &ldsA[(j * 256 + wid * 64) * 8]);
        }
        #pragma unroll
        for (int j = 0; j < 4; j++){                 // stage qT tile
            int n = j * 256 + tid;
            int row = n >> 3, c = n & 7;
            int cc = c ^ (row & 7);
            gload_lds16(Bb + (size_t)(d0 + row) * L_ + kb + cc * 8, &ldsB[(j * 256 + wid * 64) * 8]);
        }
        __syncthreads();
        #pragma unroll
        for (int kk = 0; kk < 2; kk++){
            f16x8 af[4], bf[4];
            #pragma unroll
            for (int m = 0; m < 4; m++){
                int row = wm * 64 + m * 16 + l15;
                int c = kk * 4 + l4;
                af[m] = *(const f16x8*)&ldsA[(row * 8 + (c ^ (row & 7))) * 8];
            }
            #pragma unroll
            for (int n = 0; n < 4; n++){
                int row = wn * 64 + n * 16 + l15;
                int c = kk * 4 + l4;
                bf[n] = *(const f16x8*)&ldsB[(row * 8 + (c ^ (row & 7))) * 8];
            }
            #pragma unroll
            for (int m = 0; m < 4; m++)
                #pragma unroll
                for (int n = 0; n < 4; n++)
                    acc[m][n] = __builtin_amdgcn_mfma_f32_16x16x32_f16(af[m], bf[n], acc[m][n], 0, 0, 0);
        }
        __syncthreads();
    }

    float* cRow = cB + (size_t)bb * L_ * D_;
    #pragma unroll
    for (int m = 0; m < 4; m++){
        int sbase = s0 + wm * 64 + m * 16 + l4 * 4;
        #pragma unroll
        for (int r = 0; r < 4; r++){
            int s = sbase + r;
            #pragma unroll
            for (int n = 0; n < 4; n++){
                int d = d0 + wn * 64 + n * 16 + l15;
                cRow[(size_t)s * D_ + d] = acc[m][n][r];
            }
        }
    }
}

// ---------------- epilogue: pure streaming, fully coalesced float4 ----------------
__global__ __launch_bounds__(192) void epi(const float* __restrict__ cB, const float* __restrict__ h,
    const float* __restrict__ p2, float* __restrict__ out, int b0)
{
    int rowid = blockIdx.x;                          // bb*1024 + s
    int bb = rowid >> 10, s = rowid & 1023;
    int bg = b0 + bb;
    float p2v = p2[(size_t)bg * L_ + s];
    const float* cR = cB + (size_t)rowid * D_;
    const float* hR = h + ((size_t)bg * L_ + s) * D_;
    float* oR = out + ((size_t)bg * L_ + s) * (4 * D_);
    int d = threadIdx.x * 4;
    float4 cv = *(const float4*)(cR + d);
    float4 hv = *(const float4*)(hR + d);
    float4 hc = {hv.x * cv.x, hv.y * cv.y, hv.z * cv.z, hv.w * cv.w};
    float4 qc = {p2v * hc.x, p2v * hc.y, p2v * hc.z, p2v * hc.w};
    *(float4*)(oR + d)          = hv;
    *(float4*)(oR + D_ + d)     = cv;
    *(float4*)(oR + 2 * D_ + d) = hc;
    *(float4*)(oR + 3 * D_ + d) = qc;
}

extern "C" void kernel_launch(void* const* d_in, const int* in_sizes, int n_in,
                              void* d_out, int out_size, void* d_ws, size_t ws_size,
                              hipStream_t stream)
{
    const float* h   = (const float*)d_in[0];
    const float* q   = (const float*)d_in[1];
    const float* w1w = (const float*)d_in[2];
    const float* w1b = (const float*)d_in[3];
    const float* w2w = (const float*)d_in[4];
    const float* w2b = (const float*)d_in[5];
    float* out = (float*)d_out;

    const size_t szPlane = (size_t)L_ * D_ * 2;      // one fp16 plane, 1.5 MiB
    const size_t szM     = (size_t)B_ * L_ * 4;
    const size_t perB_aB = (size_t)L_ * L_ * 4;      // 4 MiB logits
    const size_t perB_pB = (size_t)L_ * L_ * 2;      // 2 MiB fp16 p
    const size_t perB_cB = (size_t)L_ * D_ * 4;      // 3 MiB f32 c
    // per batch: hH, wH, qH, qT (4 planes) + aB + pB + cB
    const size_t perB = 4 * szPlane + perB_aB + perB_pB + perB_cB;   // 15 MiB
    const size_t fixed = szPlane + 2 * szM;          // w1h + mws + p2

    int NB = 1;
    if (ws_size > fixed){
        size_t nbc = (ws_size - fixed) / perB;
        NB = (nbc >= 16) ? 16 : (nbc < 1 ? 1 : (int)nbc);
    }

    char* p = (char*)d_ws;
    u16*   w1h  = (u16*)p;   p += szPlane;
    float* mws  = (float*)p; p += szM;
    float* p2   = (float*)p; p += szM;
    u16*   hH   = (u16*)p;   p += szPlane * NB;
    u16*   wH   = (u16*)p;   p += szPlane * NB;
    u16*   qH   = (u16*)p;   p += szPlane * NB;
    u16*   qT   = (u16*)p;   p += szPlane * NB;
    u16*   pB   = (u16*)p;   p += perB_pB * NB;
    float* cB   = (float*)p; p += perB_cB * NB;
    float* aB   = (float*)p;

    for (int b0 = 0; b0 < B_; b0 += NB){
        int nb = (B_ - b0 < NB) ? (B_ - b0) : NB;
        prep_a<<<dim3(nb * 768), 256, 0, stream>>>(h, q, w1w, w2w, hH, wH, qH, w1h, b0, nb);
        prep_t<<<dim3(32, 24, nb), dim3(32, 8), 0, stream>>>(q, qT, b0);
        gemm1 <<<dim3(64, nb), 256, 0, stream>>>(hH, wH, qH, w1h, w1b, w2b, aB);
        rowsm <<<dim3(nb * 1024), 256, 0, stream>>>(aB, pB, mws, b0);
        p2k   <<<dim3(nb), 1024, 0, stream>>>(mws, p2, b0);
        gemm2 <<<dim3(48, nb), 256, 0, stream>>>(pB, qT, cB);
        epi   <<<dim3(nb * 1024), 192, 0, stream>>>(cB, h, p2, out, b0);
    }
}

// Round 6
// 227.437 us; speedup vs baseline: 1.6255x; 1.1046x over previous
//
#include <hip/hip_runtime.h>
#include <stdint.h>

#define B_  16
#define L_  1024
#define D_  768
#define K1_ 1536

typedef unsigned short u16;
typedef __attribute__((ext_vector_type(4))) float f32x4;
typedef __attribute__((ext_vector_type(8))) _Float16 f16x8;

__device__ __forceinline__ u16 f2h(float x){
    return __builtin_bit_cast(u16, (_Float16)x);
}
__device__ __forceinline__ float h2f(u16 x){
    return (float)__builtin_bit_cast(_Float16, x);
}

__device__ __forceinline__ void gload_lds16(const void* g, void* l){
    __builtin_amdgcn_global_load_lds((const __attribute__((address_space(1))) void*)g,
                                     (__attribute__((address_space(3))) void*)l, 16, 0, 0);
}

// ---------------- prep (fused): planes hH=h, wH=h+w2, qH=q, w1h=w1 (all fp16) + qT transpose ----------------
__global__ __launch_bounds__(256) void prep(const float* __restrict__ h, const float* __restrict__ q,
    const float* __restrict__ w1w, const float* __restrict__ w2w,
    u16* __restrict__ hH, u16* __restrict__ wH, u16* __restrict__ qH,
    u16* __restrict__ w1h, u16* __restrict__ qT, int b0, int nb)
{
    __shared__ float tile[32][33];
    int bb = blockIdx.z, bg = b0 + bb;
    int t0 = blockIdx.x * 32, d0 = blockIdx.y * 32;
    int tid = threadIdx.x;
    int r  = tid >> 3;               // 0..31 (t row)
    int c4 = (tid & 7) * 4;          // 0..28 (d col, x4)
    int t = t0 + r, d = d0 + c4;
    size_t goff = (size_t)t * D_ + d;

    float4 qv  = *(const float4*)(q   + (size_t)bg * L_ * D_ + goff);
    float4 hv  = *(const float4*)(h   + (size_t)bg * L_ * D_ + goff);
    float4 w2v = *(const float4*)(w2w + goff);

    tile[r][c4 + 0] = qv.x; tile[r][c4 + 1] = qv.y;
    tile[r][c4 + 2] = qv.z; tile[r][c4 + 3] = qv.w;

    size_t o = ((size_t)bb * L_ + t) * D_ + d;
    ushort4 a;
    a.x = f2h(hv.x); a.y = f2h(hv.y); a.z = f2h(hv.z); a.w = f2h(hv.w);
    *(ushort4*)(hH + o) = a;
    a.x = f2h(hv.x + w2v.x); a.y = f2h(hv.y + w2v.y);
    a.z = f2h(hv.z + w2v.z); a.w = f2h(hv.w + w2v.w);
    *(ushort4*)(wH + o) = a;
    a.x = f2h(qv.x); a.y = f2h(qv.y); a.z = f2h(qv.z); a.w = f2h(qv.w);
    *(ushort4*)(qH + o) = a;
    if (bb == 0){
        float4 w1v = *(const float4*)(w1w + goff);
        a.x = f2h(w1v.x); a.y = f2h(w1v.y); a.z = f2h(w1v.z); a.w = f2h(w1v.w);
        *(ushort4*)(w1h + goff) = a;
    }
    __syncthreads();
    // transpose write: thread -> d-row (d0+dr), t-cols t0+tc..tc+3
    int dr = tid >> 3;               // 0..31
    int tc = (tid & 7) * 4;          // 0..28
    ushort4 b;
    b.x = f2h(tile[tc + 0][dr]); b.y = f2h(tile[tc + 1][dr]);
    b.z = f2h(tile[tc + 2][dr]); b.w = f2h(tile[tc + 3][dr]);
    *(ushort4*)(qT + (size_t)bb * D_ * L_ + (size_t)(d0 + dr) * L_ + t0 + tc) = b;
}

// ---------------- GEMM1: a = [h | h+w2] @ [w1 | q]^T + biases -> fp16 logits, XCD-grouped ----------------
__global__ __launch_bounds__(256) void gemm1(
    const u16* __restrict__ hH, const u16* __restrict__ wH,
    const u16* __restrict__ qH, const u16* __restrict__ w1h,
    const float* __restrict__ w1b, const float* __restrict__ w2b,
    u16* __restrict__ aH)
{
    __shared__ u16 ldsA[128 * 64];
    __shared__ u16 ldsB[128 * 64];
    int nwg = gridDim.x;                             // 64*nb, always %8==0
    int o = blockIdx.x;
    int wg = (o & 7) * (nwg >> 3) + (o >> 3);        // XCD batch-grouping (bijective)
    int bb = wg >> 6;
    int tl = wg & 63;
    int sm = tl >> 3, tn = tl & 7;
    int s0 = sm * 128, t0 = tn * 128;
    int tid = threadIdx.x;
    int lane = tid & 63, wid = tid >> 6;
    int wm = wid >> 1, wn = wid & 1;
    int l15 = lane & 15, l4 = lane >> 4;

    const u16* hHb = hH + (size_t)bb * L_ * D_;
    const u16* wHb = wH + (size_t)bb * L_ * D_;
    const u16* qHb = qH + (size_t)bb * L_ * D_;

    f32x4 acc[4][4];
    #pragma unroll
    for (int m = 0; m < 4; m++)
        #pragma unroll
        for (int n = 0; n < 4; n++)
            acc[m][n] = (f32x4){0.f, 0.f, 0.f, 0.f};

    for (int kb = 0; kb < K1_; kb += 64){
        bool inH = (kb < D_);
        const u16* Asrc = inH ? hHb : wHb;           // A rows (s-indexed)
        const u16* Bsrc = inH ? w1h : qHb;           // B rows (t-indexed)
        int koff = inH ? kb : (kb - D_);
        #pragma unroll
        for (int j = 0; j < 4; j++){                 // stage A + B tiles (128 rows x 64 k each)
            int n = j * 256 + tid;
            int row = n >> 3, c = n & 7;
            int cc = c ^ (row & 7);                  // pre-swizzled global chunk
            int k = koff + cc * 8;
            gload_lds16(Asrc + (size_t)(s0 + row) * D_ + k, &ldsA[(j * 256 + wid * 64) * 8]);
            gload_lds16(Bsrc + (size_t)(t0 + row) * D_ + k, &ldsB[(j * 256 + wid * 64) * 8]);
        }
        __syncthreads();
        #pragma unroll
        for (int kk = 0; kk < 2; kk++){
            f16x8 af[4], bf[4];
            #pragma unroll
            for (int m = 0; m < 4; m++){
                int row = wm * 64 + m * 16 + l15;
                int c = kk * 4 + l4;
                af[m] = *(const f16x8*)&ldsA[(row * 8 + (c ^ (row & 7))) * 8];
            }
            #pragma unroll
            for (int n = 0; n < 4; n++){
                int row = wn * 64 + n * 16 + l15;
                int c = kk * 4 + l4;
                bf[n] = *(const f16x8*)&ldsB[(row * 8 + (c ^ (row & 7))) * 8];
            }
            #pragma unroll
            for (int m = 0; m < 4; m++)
                #pragma unroll
                for (int n = 0; n < 4; n++)
                    acc[m][n] = __builtin_amdgcn_mfma_f32_16x16x32_f16(af[m], bf[n], acc[m][n], 0, 0, 0);
        }
        __syncthreads();
    }

    u16* aRow = aH + (size_t)bb * L_ * L_;
    #pragma unroll
    for (int n = 0; n < 4; n++){
        int tcol = t0 + wn * 64 + n * 16 + l15;
        float w1v = w1b[tcol];
        #pragma unroll
        for (int m = 0; m < 4; m++){
            int sbase = s0 + wm * 64 + m * 16 + l4 * 4;
            #pragma unroll
            for (int r = 0; r < 4; r++){
                int s = sbase + r;
                aRow[(size_t)s * L_ + tcol] = f2h(acc[m][n][r] + w1v + w2b[s]);
            }
        }
    }
}

// ---------------- row softmax: aH (fp16) -> pB (fp16 compact), m = rowmax ----------------
__global__ __launch_bounds__(256) void rowsm(const u16* __restrict__ aH, u16* __restrict__ pB,
                                             float* __restrict__ mws, int b0)
{
    __shared__ float red[4];
    int rowid = blockIdx.x;                          // bb*1024 + s
    int bb = rowid >> 10, s = rowid & 1023;
    const u16* row = aH + (size_t)rowid * L_;
    int tid = threadIdx.x;
    ushort4 pv = ((const ushort4*)row)[tid];
    float v0 = h2f(pv.x), v1 = h2f(pv.y), v2 = h2f(pv.z), v3 = h2f(pv.w);
    float mx = fmaxf(fmaxf(v0, v1), fmaxf(v2, v3));
    #pragma unroll
    for (int o = 32; o; o >>= 1) mx = fmaxf(mx, __shfl_xor(mx, o));
    if ((tid & 63) == 0) red[tid >> 6] = mx;
    __syncthreads();
    mx = fmaxf(fmaxf(red[0], red[1]), fmaxf(red[2], red[3]));
    float e0 = __expf(v0 - mx), e1 = __expf(v1 - mx), e2 = __expf(v2 - mx), e3 = __expf(v3 - mx);
    float sum = e0 + e1 + e2 + e3;
    #pragma unroll
    for (int o = 32; o; o >>= 1) sum += __shfl_xor(sum, o);
    __syncthreads();
    if ((tid & 63) == 0) red[tid >> 6] = sum;
    __syncthreads();
    sum = red[0] + red[1] + red[2] + red[3];
    float inv = 1.0f / sum;
    ushort4 pk;
    pk.x = f2h(e0 * inv); pk.y = f2h(e1 * inv); pk.z = f2h(e2 * inv); pk.w = f2h(e3 * inv);
    ((ushort4*)(pB + (size_t)rowid * L_))[tid] = pk;
    if (tid == 0) mws[(size_t)(b0 + bb) * L_ + s] = mx;
}

// ---------------- p2 = softmax over s of m (per batch) ----------------
__global__ __launch_bounds__(1024) void p2k(const float* __restrict__ mws, float* __restrict__ p2, int b0)
{
    __shared__ float red[16];
    int bg = b0 + blockIdx.x;
    int tid = threadIdx.x;
    float v = mws[(size_t)bg * L_ + tid];
    float mx = v;
    #pragma unroll
    for (int o = 32; o; o >>= 1) mx = fmaxf(mx, __shfl_xor(mx, o));
    if ((tid & 63) == 0) red[tid >> 6] = mx;
    __syncthreads();
    float m2 = red[0];
    #pragma unroll
    for (int i = 1; i < 16; i++) m2 = fmaxf(m2, red[i]);
    float e = __expf(v - m2);
    float sum = e;
    #pragma unroll
    for (int o = 32; o; o >>= 1) sum += __shfl_xor(sum, o);
    __syncthreads();
    if ((tid & 63) == 0) red[tid >> 6] = sum;
    __syncthreads();
    float st = 0.f;
    #pragma unroll
    for (int i = 0; i < 16; i++) st += red[i];
    p2[(size_t)bg * L_ + tid] = e / st;
}

// ---------------- GEMM2 core: c = p @ q (fp16 in, f32 dense out), XCD-grouped ----------------
__global__ __launch_bounds__(256) void gemm2(const u16* __restrict__ pB, const u16* __restrict__ qT,
    float* __restrict__ cB)
{
    __shared__ u16 ldsA[128 * 64];
    __shared__ u16 ldsB[128 * 64];
    int nwg = gridDim.x;                             // 48*nb, always %8==0
    int o = blockIdx.x;
    int wg = (o & 7) * (nwg >> 3) + (o >> 3);
    int bb = wg / 48;
    int tl = wg % 48;
    int sm = tl / 6, dn = tl % 6;
    int s0 = sm * 128, d0 = dn * 128;
    int tid = threadIdx.x;
    int lane = tid & 63, wid = tid >> 6;
    int wm = wid >> 1, wn = wid & 1;
    int l15 = lane & 15, l4 = lane >> 4;

    const u16* Ab = pB + (size_t)bb * L_ * L_;
    const u16* Bb = qT + (size_t)bb * D_ * L_;

    f32x4 acc[4][4];
    #pragma unroll
    for (int m = 0; m < 4; m++)
        #pragma unroll
        for (int n = 0; n < 4; n++)
            acc[m][n] = (f32x4){0.f, 0.f, 0.f, 0.f};

    for (int kb = 0; kb < L_; kb += 64){
        #pragma unroll
        for (int j = 0; j < 4; j++){                 // stage p tile (dense fp16, stride 2KB)
            int n = j * 256 + tid;
            int row = n >> 3, c = n & 7;
            int cc = c ^ (row & 7);
            gload_lds16(Ab + (size_t)(s0 + row) * L_ + kb + cc * 8, &ldsA[(j * 256 + wid * 64) * 8]);
        }
        #pragma unroll
        for (int j = 0; j < 4; j++){                 // stage qT tile
            int n = j * 256 + tid;
            int row = n >> 3, c = n & 7;
            int cc = c ^ (row & 7);
            gload_lds16(Bb + (size_t)(d0 + row) * L_ + kb + cc * 8, &ldsB[(j * 256 + wid * 64) * 8]);
        }
        __syncthreads();
        #pragma unroll
        for (int kk = 0; kk < 2; kk++){
            f16x8 af[4], bf[4];
            #pragma unroll
            for (int m = 0; m < 4; m++){
                int row = wm * 64 + m * 16 + l15;
                int c = kk * 4 + l4;
                af[m] = *(const f16x8*)&ldsA[(row * 8 + (c ^ (row & 7))) * 8];
            }
            #pragma unroll
            for (int n = 0; n < 4; n++){
                int row = wn * 64 + n * 16 + l15;
                int c = kk * 4 + l4;
                bf[n] = *(const f16x8*)&ldsB[(row * 8 + (c ^ (row & 7))) * 8];
            }
            #pragma unroll
            for (int m = 0; m < 4; m++)
                #pragma unroll
                for (int n = 0; n < 4; n++)
                    acc[m][n] = __builtin_amdgcn_mfma_f32_16x16x32_f16(af[m], bf[n], acc[m][n], 0, 0, 0);
        }
        __syncthreads();
    }

    float* cRow = cB + (size_t)bb * L_ * D_;
    #pragma unroll
    for (int m = 0; m < 4; m++){
        int sbase = s0 + wm * 64 + m * 16 + l4 * 4;
        #pragma unroll
        for (int r = 0; r < 4; r++){
            int s = sbase + r;
            #pragma unroll
            for (int n = 0; n < 4; n++){
                int d = d0 + wn * 64 + n * 16 + l15;
                cRow[(size_t)s * D_ + d] = acc[m][n][r];
            }
        }
    }
}

// ---------------- epilogue: pure streaming, fully coalesced float4 ----------------
__global__ __launch_bounds__(192) void epi(const float* __restrict__ cB, const float* __restrict__ h,
    const float* __restrict__ p2, float* __restrict__ out, int b0)
{
    int rowid = blockIdx.x;                          // bb*1024 + s
    int bb = rowid >> 10, s = rowid & 1023;
    int bg = b0 + bb;
    float p2v = p2[(size_t)bg * L_ + s];
    const float* cR = cB + (size_t)rowid * D_;
    const float* hR = h + ((size_t)bg * L_ + s) * D_;
    float* oR = out + ((size_t)bg * L_ + s) * (4 * D_);
    int d = threadIdx.x * 4;
    float4 cv = *(const float4*)(cR + d);
    float4 hv = *(const float4*)(hR + d);
    float4 hc = {hv.x * cv.x, hv.y * cv.y, hv.z * cv.z, hv.w * cv.w};
    float4 qc = {p2v * hc.x, p2v * hc.y, p2v * hc.z, p2v * hc.w};
    *(float4*)(oR + d)          = hv;
    *(float4*)(oR + D_ + d)     = cv;
    *(float4*)(oR + 2 * D_ + d) = hc;
    *(float4*)(oR + 3 * D_ + d) = qc;
}

extern "C" void kernel_launch(void* const* d_in, const int* in_sizes, int n_in,
                              void* d_out, int out_size, void* d_ws, size_t ws_size,
                              hipStream_t stream)
{
    const float* h   = (const float*)d_in[0];
    const float* q   = (const float*)d_in[1];
    const float* w1w = (const float*)d_in[2];
    const float* w1b = (const float*)d_in[3];
    const float* w2w = (const float*)d_in[4];
    const float* w2b = (const float*)d_in[5];
    float* out = (float*)d_out;

    const size_t szPlane = (size_t)L_ * D_ * 2;      // one fp16 plane, 1.5 MiB
    const size_t szM     = (size_t)B_ * L_ * 4;
    const size_t perB_aH = (size_t)L_ * L_ * 2;      // 2 MiB fp16 logits
    const size_t perB_pB = (size_t)L_ * L_ * 2;      // 2 MiB fp16 p
    const size_t perB_cB = (size_t)L_ * D_ * 4;      // 3 MiB f32 c
    // per batch: hH, wH, qH, qT (4 planes) + aH + pB + cB
    const size_t perB = 4 * szPlane + perB_aH + perB_pB + perB_cB;   // 13 MiB
    const size_t fixed = szPlane + 2 * szM;          // w1h + mws + p2

    int NB = 1;
    if (ws_size > fixed){
        size_t nbc = (ws_size - fixed) / perB;
        NB = (nbc >= 16) ? 16 : (nbc < 1 ? 1 : (int)nbc);
    }

    char* p = (char*)d_ws;
    u16*   w1h  = (u16*)p;   p += szPlane;
    float* mws  = (float*)p; p += szM;
    float* p2   = (float*)p; p += szM;
    u16*   hH   = (u16*)p;   p += szPlane * NB;
    u16*   wH   = (u16*)p;   p += szPlane * NB;
    u16*   qH   = (u16*)p;   p += szPlane * NB;
    u16*   qT   = (u16*)p;   p += szPlane * NB;
    u16*   pB   = (u16*)p;   p += perB_pB * NB;
    float* cB   = (float*)p; p += perB_cB * NB;
    u16*   aH   = (u16*)p;

    for (int b0 = 0; b0 < B_; b0 += NB){
        int nb = (B_ - b0 < NB) ? (B_ - b0) : NB;
        prep  <<<dim3(32, 24, nb), 256, 0, stream>>>(h, q, w1w, w2w, hH, wH, qH, w1h, qT, b0, nb);
        gemm1 <<<dim3(64 * nb), 256, 0, stream>>>(hH, wH, qH, w1h, w1b, w2b, aH);
        rowsm <<<dim3(nb * 1024), 256, 0, stream>>>(aH, pB, mws, b0);
        p2k   <<<dim3(nb), 1024, 0, stream>>>(mws, p2, b0);
        gemm2 <<<dim3(48 * nb), 256, 0, stream>>>(pB, qT, cB);
        epi   <<<dim3(nb * 1024), 192, 0, stream>>>(cB, h, p2, out, b0);
    }
}